// Round 10
// baseline (300.395 us; speedup 1.0000x reference)
//
#include <hip/hip_runtime.h>
#include <hip/hip_bf16.h>
#include <hip/hip_fp16.h>

typedef __attribute__((ext_vector_type(8))) short bf16x8;
typedef __attribute__((ext_vector_type(4))) float f32x4;

// ---------------- weight transforms -------------------------------------------
// w1 [64][3][3][3] f32 -> w1t [64][32] bf16 (k = ic*9+ky*3+kx, pad 27..31 = 0)
// w2 [128][64][3][3] f32 -> w2h [9][2][4][128][8] bf16 panels
__global__ void wt_xform_all(const float* __restrict__ w1, const float* __restrict__ w2,
                             __hip_bfloat16* __restrict__ w1t, __hip_bfloat16* __restrict__ w2h) {
    int i = blockIdx.x * 256 + threadIdx.x;
    if (i < 2048) {
        int oc = i >> 5, k = i & 31;
        w1t[i] = (k < 27) ? __float2bfloat16(w1[oc * 27 + k]) : __float2bfloat16(0.f);
        return;
    }
    int j = i - 2048;
    if (j < 9 * 2 * 4 * 128 * 8) {
        int e  = j & 7;
        int oc = (j >> 3) & 127;
        int c  = (j >> 10) & 3;
        int h  = (j >> 12) & 1;
        int kk = j >> 13;
        int ic = h * 32 + c * 8 + e;
        int ky = kk / 3, kx = kk - ky * 3;
        w2h[j] = __float2bfloat16(w2[(((size_t)oc * 64 + ic) * 3 + ky) * 3 + kx]);
    }
}

// ---------------- conv1 implicit-GEMM on MFMA + fused bias/relu/maxpool ---------
__global__ void __launch_bounds__(256, 2)
conv1_mfma(const float* __restrict__ in,
           const __hip_bfloat16* __restrict__ w1t,
           const float* __restrict__ bias,
           __hip_bfloat16* __restrict__ out,
           int Hin, int Win, int PH, int PW, int tilesX) {
    __shared__ unsigned short xs[3 * 324];   // [ic][18 rows][18 cols] bf16 bits
    int t = threadIdx.x;
    int tile = blockIdx.x;
    int tileY = tile / tilesX, tileX = tile - tileY * tilesX;
    int b = blockIdx.z;
    int y0 = tileY * 16, x0 = tileX * 16;

    const float* inb = in + (size_t)b * 3 * Hin * Win;
    for (int i = t; i < 972; i += 256) {
        int ic = i / 324, rem = i - ic * 324;
        int r = rem / 18, c = rem - r * 18;
        int gy = y0 + r, gx = x0 + c;
        float v = 0.f;
        if (gy < Hin && gx < Win) v = inb[((size_t)ic * Hin + gy) * Win + gx];
        __hip_bfloat16 hv = __float2bfloat16(v);
        xs[i] = *(unsigned short*)&hv;
    }
    __syncthreads();

    int lane = t & 63, wv = t >> 6;
    int l15 = lane & 15, l4 = lane >> 4;

    bf16x8 af[4];
#pragma unroll
    for (int m = 0; m < 4; ++m)
        af[m] = *(const bf16x8*)&w1t[((size_t)(m * 16 + l15)) * 32 + l4 * 8];

    int off0, off1, off2, off3, off4, off5, off6, off7;
    int ok0, ok1, ok2, ok3, ok4, ok5, ok6, ok7;
#define MKOFF(J) { int kk = l4 * 8 + J; int ic = kk / 9; int r9 = kk - ic * 9; \
                   int ky = r9 / 3; int kx = r9 - ky * 3; \
                   ok##J = (kk < 27); off##J = ok##J ? (ic * 324 + ky * 18 + kx) : 0; }
    MKOFF(0) MKOFF(1) MKOFF(2) MKOFF(3) MKOFF(4) MKOFF(5) MKOFF(6) MKOFF(7)
#undef MKOFF

    f32x4 acc[4][4];
#pragma unroll
    for (int m = 0; m < 4; ++m)
#pragma unroll
        for (int n = 0; n < 4; ++n) acc[m][n] = (f32x4)(0.f);

#pragma unroll
    for (int n = 0; n < 4; ++n) {
        int y = wv * 4 + n;
        int base = y * 18 + l15;
        bf16x8 bfr;
        bfr[0] = ok0 ? (short)xs[base + off0] : (short)0;
        bfr[1] = ok1 ? (short)xs[base + off1] : (short)0;
        bfr[2] = ok2 ? (short)xs[base + off2] : (short)0;
        bfr[3] = ok3 ? (short)xs[base + off3] : (short)0;
        bfr[4] = ok4 ? (short)xs[base + off4] : (short)0;
        bfr[5] = ok5 ? (short)xs[base + off5] : (short)0;
        bfr[6] = ok6 ? (short)xs[base + off6] : (short)0;
        bfr[7] = ok7 ? (short)xs[base + off7] : (short)0;
#pragma unroll
        for (int m = 0; m < 4; ++m)
            acc[m][n] = __builtin_amdgcn_mfma_f32_16x16x32_bf16(af[m], bfr, acc[m][n], 0, 0, 0);
    }

    int qx = tileX * 8 + (l15 >> 1);
    bool xok = ((lane & 1) == 0) && (qx < PW);
#pragma unroll
    for (int m = 0; m < 4; ++m) {
        int ocb = m * 16 + l4 * 4;
#pragma unroll
        for (int np = 0; np < 2; ++np) {
            int qy = tileY * 8 + wv * 2 + np;
            union { __hip_bfloat16 h[4]; uint2 v; } pk;
#pragma unroll
            for (int r = 0; r < 4; ++r) {
                float v = fmaxf(acc[m][2 * np][r], acc[m][2 * np + 1][r]);
                v = fmaxf(v, __shfl_xor(v, 1));
                pk.h[r] = __float2bfloat16(fmaxf(v + bias[ocb + r], 0.f));
            }
            if (xok && qy < PH)
                *(uint2*)&out[(((size_t)b * PH + qy) * PW + qx) * 64 + ocb] = pk.v;
        }
    }
}

// ---------------- conv2 implicit-GEMM: 18-phase ic-half A-dbuf, 4 blocks/CU ------
// Templated output type: __half for xf (feature map), float for k-planes
// (xcorr consumes k via scalar s_loads -> wants f32 directly).
template <typename OT>
__global__ void __launch_bounds__(256, 4)
conv2_mfma(const __hip_bfloat16* __restrict__ xin,
           const __hip_bfloat16* __restrict__ w2h,
           const float* __restrict__ bias, OT* __restrict__ out,
           int H1, int W1, int PH, int PW, int tilesY) {
    __shared__ uint4 xl4[10 * 18 * 8];   // 23040 B input tile; reused as store buffer
    __shared__ uint4 aw[2][512];         // 2 x 8 KB weight half-panels

    int t = threadIdx.x;
    int tile = blockIdx.x;
    int tileY = tile % tilesY, tileX = tile / tilesY;
    int b = blockIdx.z;
    int y0 = tileY * 8, x0 = tileX * 16;

    const __hip_bfloat16* xb = xin + (size_t)b * H1 * W1 * 64;
    for (int s = t; s < 1440; s += 256) {
        int pixel = s >> 3, si = s & 7;
        int row = pixel / 18, col = pixel - row * 18;
        int gy = y0 + row, gx = x0 + col;
        uint4 v = make_uint4(0, 0, 0, 0);
        if (gy < H1 && gx < W1)
            v = *(const uint4*)&xb[((size_t)gy * W1 + gx) * 64 + si * 8];
        xl4[(pixel << 3) | (si ^ (col & 7))] = v;
    }
    {
        const uint4* src = (const uint4*)w2h;
        aw[0][t] = src[t];
        aw[0][t + 256] = src[t + 256];
    }
    __syncthreads();

    int lane = t & 63;
    int wid = t >> 6;
    int wr = wid >> 1;
    int wc = wid & 1;
    int l15 = lane & 15, l4 = lane >> 4;

    f32x4 acc[4][4];
#pragma unroll
    for (int m = 0; m < 4; ++m)
#pragma unroll
        for (int n = 0; n < 4; ++n) acc[m][n] = (f32x4)(0.f);

    for (int p = 0; p < 18; ++p) {
        const int cur = p & 1;
        const int kk = p >> 1, h = p & 1;

        uint4 pf0, pf1;
        if (p < 17) {
            const uint4* src = (const uint4*)w2h + (size_t)(p + 1) * 512;
            pf0 = src[t];
            pf1 = src[t + 256];
        }

        const int ky = kk / 3, kx = kk - ky * 3;
        const int col = l15 + kx;
        const int sidx = (h * 4 + l4) ^ (col & 7);

        bf16x8 af[4], bfv[4];
#pragma unroll
        for (int m = 0; m < 4; ++m) {
            int oc = wr * 64 + m * 16 + l15;
            af[m] = *(const bf16x8*)&aw[cur][l4 * 128 + oc];
        }
#pragma unroll
        for (int n = 0; n < 4; ++n) {
            int row = wc * 4 + n + ky;
            bfv[n] = *(const bf16x8*)&xl4[((row * 18 + col) << 3) | sidx];
        }
#pragma unroll
        for (int m = 0; m < 4; ++m)
#pragma unroll
            for (int n = 0; n < 4; ++n)
                acc[m][n] = __builtin_amdgcn_mfma_f32_16x16x32_bf16(
                    af[m], bfv[n], acc[m][n], 0, 0, 0);

        if (p < 17) {
            aw[cur ^ 1][t] = pf0;
            aw[cur ^ 1][t + 256] = pf1;
        }
        __syncthreads();
    }

    // epilogue: pool + bias + relu -> LDS -> contiguous NCHW stores
    OT* plds = (OT*)xl4;
#pragma unroll
    for (int m = 0; m < 4; ++m) {
        int ocb = wr * 64 + m * 16 + l4 * 4;
#pragma unroll
        for (int np = 0; np < 2; ++np) {
            int qyl = wc * 2 + np;
#pragma unroll
            for (int r = 0; r < 4; ++r) {
                float v = fmaxf(acc[m][2 * np][r], acc[m][2 * np + 1][r]);
                v = fmaxf(v, __shfl_xor(v, 1));
                if ((lane & 1) == 0) {
                    float u = fmaxf(v + bias[ocb + r], 0.f);
                    if constexpr (sizeof(OT) == 2)
                        plds[((ocb + r) * 4 + qyl) * 8 + (l15 >> 1)] = (OT)__float2half(u);
                    else
                        plds[((ocb + r) * 4 + qyl) * 8 + (l15 >> 1)] = (OT)u;
                }
            }
        }
    }
    __syncthreads();

    int qx0 = tileX * 8, qy0 = tileY * 4;
    for (int i = t; i < 512; i += 256) {
        int oc = i >> 2, qy = i & 3;
        int gqy = qy0 + qy;
        if (gqy < PH) {
            OT* dst = out + (((size_t)b * 128 + oc) * PH + gqy) * PW + qx0;
            const OT* src = &plds[i * 8];
            if (qx0 + 8 <= PW) {
                if constexpr (sizeof(OT) == 2) {
                    *(uint4*)dst = *(const uint4*)src;
                } else {
#pragma unroll
                    for (int q = 0; q < 8; q += 2)
                        *(float2*)((float*)dst + q) = *(const float2*)((const float*)src + q);
                }
            } else {
                for (int q = 0; q < 8 && qx0 + q < PW; ++q) dst[q] = src[q];
            }
        }
    }
}

// ---------------- fused dual depthwise xcorr, f32 fmac -----------------------
// R9 lesson: v_dot2_f32_f16 is half-rate on gfx950 (2 MAC / 4 cyc = fmac rate),
// so packed f16 bought nothing and cost 10 align-ops/ky. Now: x staged as f32
// in LDS, kernels read as f32 via uniform s_loads, inner loop = pure
// v_fmac_f32 v,s,v (224/ky, fully unrolled). ~2x fewer VALU cycles.
__global__ void __launch_bounds__(384, 4)
xcorr_dual(const __half* __restrict__ x, const float* __restrict__ k1,
           const float* __restrict__ k2,
           float* __restrict__ out1, float* __restrict__ out2) {
    __shared__ float xl[62 * 66 + 8];
    int bc = blockIdx.x;
    int t = threadIdx.x;

    const unsigned* xp = (const unsigned*)(x + (size_t)bc * 3844);
    for (int d = t; d < 1922; d += 384) {
        int r = d / 31, c2 = d - r * 31;
        unsigned u = xp[d];
        __half2 h2 = *(__half2*)&u;
        float2 f = __half22float2(h2);
        *(float2*)&xl[r * 66 + 2 * c2] = f;
    }
    const float* kg1 = k1 + (size_t)bc * 196;   // uniform -> s_load
    const float* kg2 = k2 + (size_t)bc * 196;
    __syncthreads();

    if (t >= 343) return;
    int py = t % 49;
    int px0 = (t / 49) * 8;

    float a10 = 0.f, a11 = 0.f, a12 = 0.f, a13 = 0.f;
    float a14 = 0.f, a15 = 0.f, a16 = 0.f, a17 = 0.f;
    float a20 = 0.f, a21 = 0.f, a22 = 0.f, a23 = 0.f;
    float a24 = 0.f, a25 = 0.f, a26 = 0.f, a27 = 0.f;

    for (int ky = 0; ky < 14; ++ky) {
        const float* row = &xl[(py + ky) * 66 + px0];
        float2 q0 = *(const float2*)(row);
        float2 q1 = *(const float2*)(row + 2);
        float2 q2 = *(const float2*)(row + 4);
        float2 q3 = *(const float2*)(row + 6);
        float2 q4 = *(const float2*)(row + 8);
        float2 q5 = *(const float2*)(row + 10);
        float2 q6 = *(const float2*)(row + 12);
        float2 q7 = *(const float2*)(row + 14);
        float2 q8 = *(const float2*)(row + 16);
        float2 q9 = *(const float2*)(row + 18);
        float2 qa = *(const float2*)(row + 20);
        float w0 = q0.x, w1 = q0.y, w2 = q1.x, w3 = q1.y;
        float w4 = q2.x, w5 = q2.y, w6 = q3.x, w7 = q3.y;
        float w8 = q4.x, w9 = q4.y, w10 = q5.x, w11 = q5.y;
        float w12 = q6.x, w13 = q6.y, w14 = q7.x, w15 = q7.y;
        float w16 = q8.x, w17 = q8.y, w18 = q9.x, w19 = q9.y;
        float w20 = qa.x;
        const float* kr1 = kg1 + ky * 14;
        const float* kr2 = kg2 + ky * 14;
#define ST(P, A, B, C, D, E, F, G, H) do { \
        float ka = kr1[P], kb = kr2[P]; \
        a10 = fmaf(ka, A, a10); a11 = fmaf(ka, B, a11); \
        a12 = fmaf(ka, C, a12); a13 = fmaf(ka, D, a13); \
        a14 = fmaf(ka, E, a14); a15 = fmaf(ka, F, a15); \
        a16 = fmaf(ka, G, a16); a17 = fmaf(ka, H, a17); \
        a20 = fmaf(kb, A, a20); a21 = fmaf(kb, B, a21); \
        a22 = fmaf(kb, C, a22); a23 = fmaf(kb, D, a23); \
        a24 = fmaf(kb, E, a24); a25 = fmaf(kb, F, a25); \
        a26 = fmaf(kb, G, a26); a27 = fmaf(kb, H, a27); \
        } while (0)
        ST(0,  w0,  w1,  w2,  w3,  w4,  w5,  w6,  w7);
        ST(1,  w1,  w2,  w3,  w4,  w5,  w6,  w7,  w8);
        ST(2,  w2,  w3,  w4,  w5,  w6,  w7,  w8,  w9);
        ST(3,  w3,  w4,  w5,  w6,  w7,  w8,  w9,  w10);
        ST(4,  w4,  w5,  w6,  w7,  w8,  w9,  w10, w11);
        ST(5,  w5,  w6,  w7,  w8,  w9,  w10, w11, w12);
        ST(6,  w6,  w7,  w8,  w9,  w10, w11, w12, w13);
        ST(7,  w7,  w8,  w9,  w10, w11, w12, w13, w14);
        ST(8,  w8,  w9,  w10, w11, w12, w13, w14, w15);
        ST(9,  w9,  w10, w11, w12, w13, w14, w15, w16);
        ST(10, w10, w11, w12, w13, w14, w15, w16, w17);
        ST(11, w11, w12, w13, w14, w15, w16, w17, w18);
        ST(12, w12, w13, w14, w15, w16, w17, w18, w19);
        ST(13, w13, w14, w15, w16, w17, w18, w19, w20);
#undef ST
    }

    size_t ob = (size_t)bc * 2401 + (size_t)py * 49 + px0;
    out1[ob] = a10; out2[ob] = a20;
    if (px0 < 48) {
        out1[ob + 1] = a11; out1[ob + 2] = a12; out1[ob + 3] = a13;
        out1[ob + 4] = a14; out1[ob + 5] = a15; out1[ob + 6] = a16; out1[ob + 7] = a17;
        out2[ob + 1] = a21; out2[ob + 2] = a22; out2[ob + 3] = a23;
        out2[ob + 4] = a24; out2[ob + 5] = a25; out2[ob + 6] = a26; out2[ob + 7] = a27;
    }
}

extern "C" void kernel_launch(void* const* d_in, const int* in_sizes, int n_in,
                              void* d_out, int out_size, void* d_ws, size_t ws_size,
                              hipStream_t stream) {
    const float* img = (const float*)d_in[0];
    const float* t1  = (const float*)d_in[1];
    const float* t2  = (const float*)d_in[2];
    const float* w1  = (const float*)d_in[3];
    const float* b1  = (const float*)d_in[4];
    const float* w2  = (const float*)d_in[5];
    const float* b2  = (const float*)d_in[6];
    float* out = (float*)d_out;

    char* ws = (char*)d_ws;
    __hip_bfloat16* bufA = (__hip_bfloat16*)ws;                 // 66,064,384 B (image phase)
    // k1f/k2f live in bufA's dead middle: template conv1 uses only bufA[0..3.9MB],
    // and image-phase bufA is dead by the time these are written.
    float* k1f = (float*)(ws + 33554432);                       // 3,211,264 B
    float* k2f = (float*)(ws + 36765696);                       // 3,211,264 B
    __hip_bfloat16* w1t  = (__hip_bfloat16*)(ws + 66064384);    // 4,096 B
    __hip_bfloat16* w2h  = (__hip_bfloat16*)(ws + 66068480);    // 147,456 B
    __half* xf = (__half*)(ws + 66215936);                      // 31,490,048 B -> end 97.7 MB

    wt_xform_all<<<296, 256, 0, stream>>>(w1, w2, w1t, w2h);

    conv1_mfma<<<dim3(256, 1, 32), 256, 0, stream>>>(img, w1t, b1, bufA,
                                                     256, 256, 127, 127, 16);
    conv2_mfma<__half><<<dim3(128, 1, 32), 256, 0, stream>>>(bufA, w2h, b2, xf,
                                                             127, 127, 62, 62, 16);

    conv1_mfma<<<dim3(16, 1, 32), 256, 0, stream>>>(t1, w1t, b1, bufA,
                                                    64, 64, 31, 31, 4);
    conv2_mfma<float><<<dim3(8, 1, 32), 256, 0, stream>>>(bufA, w2h, b2, k1f,
                                                          31, 31, 14, 14, 4);
    conv1_mfma<<<dim3(16, 1, 32), 256, 0, stream>>>(t2, w1t, b1, bufA,
                                                    64, 64, 31, 31, 4);
    conv2_mfma<float><<<dim3(8, 1, 32), 256, 0, stream>>>(bufA, w2h, b2, k2f,
                                                          31, 31, 14, 14, 4);

    xcorr_dual<<<4096, 384, 0, stream>>>(xf, k1f, k2f, out, out + (size_t)9834496);
}

// Round 11
// 285.479 us; speedup vs baseline: 1.0522x; 1.0522x over previous
//
#include <hip/hip_runtime.h>
#include <hip/hip_bf16.h>
#include <hip/hip_fp16.h>

typedef __attribute__((ext_vector_type(8))) short bf16x8;
typedef __attribute__((ext_vector_type(4))) float f32x4;
typedef __attribute__((ext_vector_type(2))) _Float16 f16x2;

__device__ __forceinline__ float dot2f16(unsigned a, unsigned b, float c) {
#if __has_builtin(__builtin_amdgcn_fdot2)
    return __builtin_amdgcn_fdot2(__builtin_bit_cast(f16x2, a),
                                  __builtin_bit_cast(f16x2, b), c, false);
#else
    union { unsigned u; __half2 h; } ua, ub;
    ua.u = a; ub.u = b;
    return c + __low2float(ua.h) * __low2float(ub.h)
             + __high2float(ua.h) * __high2float(ub.h);
#endif
}

// ---------------- weight transforms -------------------------------------------
// w1 [64][3][3][3] f32 -> w1t [64][32] bf16 (k = ic*9+ky*3+kx, pad 27..31 = 0)
// w2 [128][64][3][3] f32 -> w2h [9][2][4][128][8] bf16 panels
__global__ void wt_xform_all(const float* __restrict__ w1, const float* __restrict__ w2,
                             __hip_bfloat16* __restrict__ w1t, __hip_bfloat16* __restrict__ w2h) {
    int i = blockIdx.x * 256 + threadIdx.x;
    if (i < 2048) {
        int oc = i >> 5, k = i & 31;
        w1t[i] = (k < 27) ? __float2bfloat16(w1[oc * 27 + k]) : __float2bfloat16(0.f);
        return;
    }
    int j = i - 2048;
    if (j < 9 * 2 * 4 * 128 * 8) {
        int e  = j & 7;
        int oc = (j >> 3) & 127;
        int c  = (j >> 10) & 3;
        int h  = (j >> 12) & 1;
        int kk = j >> 13;
        int ic = h * 32 + c * 8 + e;
        int ky = kk / 3, kx = kk - ky * 3;
        w2h[j] = __float2bfloat16(w2[(((size_t)oc * 64 + ic) * 3 + ky) * 3 + kx]);
    }
}

// ---------------- conv1 implicit-GEMM on MFMA + fused bias/relu/maxpool ---------
__global__ void __launch_bounds__(256, 2)
conv1_mfma(const float* __restrict__ in,
           const __hip_bfloat16* __restrict__ w1t,
           const float* __restrict__ bias,
           __hip_bfloat16* __restrict__ out,
           int Hin, int Win, int PH, int PW, int tilesX) {
    __shared__ unsigned short xs[3 * 324];   // [ic][18 rows][18 cols] bf16 bits
    int t = threadIdx.x;
    int tile = blockIdx.x;
    int tileY = tile / tilesX, tileX = tile - tileY * tilesX;
    int b = blockIdx.z;
    int y0 = tileY * 16, x0 = tileX * 16;

    const float* inb = in + (size_t)b * 3 * Hin * Win;
    for (int i = t; i < 972; i += 256) {
        int ic = i / 324, rem = i - ic * 324;
        int r = rem / 18, c = rem - r * 18;
        int gy = y0 + r, gx = x0 + c;
        float v = 0.f;
        if (gy < Hin && gx < Win) v = inb[((size_t)ic * Hin + gy) * Win + gx];
        __hip_bfloat16 hv = __float2bfloat16(v);
        xs[i] = *(unsigned short*)&hv;
    }
    __syncthreads();

    int lane = t & 63, wv = t >> 6;
    int l15 = lane & 15, l4 = lane >> 4;

    bf16x8 af[4];
#pragma unroll
    for (int m = 0; m < 4; ++m)
        af[m] = *(const bf16x8*)&w1t[((size_t)(m * 16 + l15)) * 32 + l4 * 8];

    int off0, off1, off2, off3, off4, off5, off6, off7;
    int ok0, ok1, ok2, ok3, ok4, ok5, ok6, ok7;
#define MKOFF(J) { int kk = l4 * 8 + J; int ic = kk / 9; int r9 = kk - ic * 9; \
                   int ky = r9 / 3; int kx = r9 - ky * 3; \
                   ok##J = (kk < 27); off##J = ok##J ? (ic * 324 + ky * 18 + kx) : 0; }
    MKOFF(0) MKOFF(1) MKOFF(2) MKOFF(3) MKOFF(4) MKOFF(5) MKOFF(6) MKOFF(7)
#undef MKOFF

    f32x4 acc[4][4];
#pragma unroll
    for (int m = 0; m < 4; ++m)
#pragma unroll
        for (int n = 0; n < 4; ++n) acc[m][n] = (f32x4)(0.f);

#pragma unroll
    for (int n = 0; n < 4; ++n) {
        int y = wv * 4 + n;
        int base = y * 18 + l15;
        bf16x8 bfr;
        bfr[0] = ok0 ? (short)xs[base + off0] : (short)0;
        bfr[1] = ok1 ? (short)xs[base + off1] : (short)0;
        bfr[2] = ok2 ? (short)xs[base + off2] : (short)0;
        bfr[3] = ok3 ? (short)xs[base + off3] : (short)0;
        bfr[4] = ok4 ? (short)xs[base + off4] : (short)0;
        bfr[5] = ok5 ? (short)xs[base + off5] : (short)0;
        bfr[6] = ok6 ? (short)xs[base + off6] : (short)0;
        bfr[7] = ok7 ? (short)xs[base + off7] : (short)0;
#pragma unroll
        for (int m = 0; m < 4; ++m)
            acc[m][n] = __builtin_amdgcn_mfma_f32_16x16x32_bf16(af[m], bfr, acc[m][n], 0, 0, 0);
    }

    int qx = tileX * 8 + (l15 >> 1);
    bool xok = ((lane & 1) == 0) && (qx < PW);
#pragma unroll
    for (int m = 0; m < 4; ++m) {
        int ocb = m * 16 + l4 * 4;
#pragma unroll
        for (int np = 0; np < 2; ++np) {
            int qy = tileY * 8 + wv * 2 + np;
            union { __hip_bfloat16 h[4]; uint2 v; } pk;
#pragma unroll
            for (int r = 0; r < 4; ++r) {
                float v = fmaxf(acc[m][2 * np][r], acc[m][2 * np + 1][r]);
                v = fmaxf(v, __shfl_xor(v, 1));
                pk.h[r] = __float2bfloat16(fmaxf(v + bias[ocb + r], 0.f));
            }
            if (xok && qy < PH)
                *(uint2*)&out[(((size_t)b * PH + qy) * PW + qx) * 64 + ocb] = pk.v;
        }
    }
}

// ---------------- conv2 implicit-GEMM: 18-phase ic-half A-dbuf, 4 blocks/CU ------
__global__ void __launch_bounds__(256, 4)
conv2_mfma(const __hip_bfloat16* __restrict__ xin,
           const __hip_bfloat16* __restrict__ w2h,
           const float* __restrict__ bias, __half* __restrict__ out,
           int H1, int W1, int PH, int PW, int tilesY) {
    __shared__ uint4 xl4[10 * 18 * 8];   // 23040 B input tile; reused as store buffer
    __shared__ uint4 aw[2][512];         // 2 x 8 KB weight half-panels

    int t = threadIdx.x;
    int tile = blockIdx.x;
    int tileY = tile % tilesY, tileX = tile / tilesY;
    int b = blockIdx.z;
    int y0 = tileY * 8, x0 = tileX * 16;

    const __hip_bfloat16* xb = xin + (size_t)b * H1 * W1 * 64;
    for (int s = t; s < 1440; s += 256) {
        int pixel = s >> 3, si = s & 7;
        int row = pixel / 18, col = pixel - row * 18;
        int gy = y0 + row, gx = x0 + col;
        uint4 v = make_uint4(0, 0, 0, 0);
        if (gy < H1 && gx < W1)
            v = *(const uint4*)&xb[((size_t)gy * W1 + gx) * 64 + si * 8];
        xl4[(pixel << 3) | (si ^ (col & 7))] = v;
    }
    {
        const uint4* src = (const uint4*)w2h;
        aw[0][t] = src[t];
        aw[0][t + 256] = src[t + 256];
    }
    __syncthreads();

    int lane = t & 63;
    int wid = t >> 6;
    int wr = wid >> 1;
    int wc = wid & 1;
    int l15 = lane & 15, l4 = lane >> 4;

    f32x4 acc[4][4];
#pragma unroll
    for (int m = 0; m < 4; ++m)
#pragma unroll
        for (int n = 0; n < 4; ++n) acc[m][n] = (f32x4)(0.f);

    for (int p = 0; p < 18; ++p) {
        const int cur = p & 1;
        const int kk = p >> 1, h = p & 1;

        uint4 pf0, pf1;
        if (p < 17) {
            const uint4* src = (const uint4*)w2h + (size_t)(p + 1) * 512;
            pf0 = src[t];
            pf1 = src[t + 256];
        }

        const int ky = kk / 3, kx = kk - ky * 3;
        const int col = l15 + kx;
        const int sidx = (h * 4 + l4) ^ (col & 7);

        bf16x8 af[4], bfv[4];
#pragma unroll
        for (int m = 0; m < 4; ++m) {
            int oc = wr * 64 + m * 16 + l15;
            af[m] = *(const bf16x8*)&aw[cur][l4 * 128 + oc];
        }
#pragma unroll
        for (int n = 0; n < 4; ++n) {
            int row = wc * 4 + n + ky;
            bfv[n] = *(const bf16x8*)&xl4[((row * 18 + col) << 3) | sidx];
        }
#pragma unroll
        for (int m = 0; m < 4; ++m)
#pragma unroll
            for (int n = 0; n < 4; ++n)
                acc[m][n] = __builtin_amdgcn_mfma_f32_16x16x32_bf16(
                    af[m], bfv[n], acc[m][n], 0, 0, 0);

        if (p < 17) {
            aw[cur ^ 1][t] = pf0;
            aw[cur ^ 1][t + 256] = pf1;
        }
        __syncthreads();
    }

    __half* plds = (__half*)xl4;
#pragma unroll
    for (int m = 0; m < 4; ++m) {
        int ocb = wr * 64 + m * 16 + l4 * 4;
#pragma unroll
        for (int np = 0; np < 2; ++np) {
            int qyl = wc * 2 + np;
#pragma unroll
            for (int r = 0; r < 4; ++r) {
                float v = fmaxf(acc[m][2 * np][r], acc[m][2 * np + 1][r]);
                v = fmaxf(v, __shfl_xor(v, 1));
                if ((lane & 1) == 0) {
                    float u = fmaxf(v + bias[ocb + r], 0.f);
                    plds[((ocb + r) * 4 + qyl) * 8 + (l15 >> 1)] = __float2half(u);
                }
            }
        }
    }
    __syncthreads();

    int qx0 = tileX * 8, qy0 = tileY * 4;
    for (int i = t; i < 512; i += 256) {
        int oc = i >> 2, qy = i & 3;
        int gqy = qy0 + qy;
        if (gqy < PH) {
            __half* dst = out + (((size_t)b * 128 + oc) * PH + gqy) * PW + qx0;
            const __half* src = &plds[i * 8];
            if (qx0 + 8 <= PW) {
                *(uint4*)dst = *(const uint4*)src;
            } else {
                for (int q = 0; q < 8 && qx0 + q < PW; ++q) dst[q] = src[q];
            }
        }
    }
}

// ---------------- fused dual depthwise xcorr, packed f16 pk_fma ------------------
// R10 lesson: dot2_f32_f16 (4cyc) and fmac_f32 (2cyc) both give 0.5 MAC/cyc.
// v_pk_fma_f16 gives 1.0 MAC/cyc. x staged f16 (33-dword pitch, conflict-free);
// kernels read as packed-f16 dwords via uniform s_load (SGPR broadcast into
// VOP3P). f16 accumulation only spans a 2-ky-row group (14 non-negative taps),
// then exact fold into f32 via fdot2(racc,(1,1)).
__global__ void __launch_bounds__(384, 4)
xcorr_dual(const __half* __restrict__ x, const __half* __restrict__ k1,
           const __half* __restrict__ k2,
           float* __restrict__ out1, float* __restrict__ out2) {
    __shared__ __half xl[62 * 66 + 8];
    int bc = blockIdx.x;
    int t = threadIdx.x;

    const unsigned* xp = (const unsigned*)(x + (size_t)bc * 3844);
    unsigned* xld = (unsigned*)xl;
    for (int d = t; d < 1922; d += 384) {
        int r = d / 31, c2 = d - r * 31;
        xld[r * 33 + c2] = xp[d];
    }
    const unsigned* kg1 = (const unsigned*)(k1 + (size_t)bc * 196);  // uniform -> s_load
    const unsigned* kg2 = (const unsigned*)(k2 + (size_t)bc * 196);
    __syncthreads();

    if (t >= 343) return;
    int py = t % 49;
    int g = t / 49;              // strip 0..6, px0 = 8g
    int px0 = g * 8;

    float f10 = 0.f, f11 = 0.f, f12 = 0.f, f13 = 0.f;
    float f14 = 0.f, f15 = 0.f, f16_ = 0.f, f17 = 0.f;
    float f20 = 0.f, f21 = 0.f, f22 = 0.f, f23 = 0.f;
    float f24 = 0.f, f25 = 0.f, f26 = 0.f, f27 = 0.f;

#define H2(u) __builtin_bit_cast(__half2, (unsigned)(u))
#define U2(h) __builtin_bit_cast(unsigned, (h))

    __half2 r10, r11, r12, r13, r14, r15, r16, r17;
    __half2 r20, r21, r22, r23, r24, r25, r26, r27;

    for (int kp = 0; kp < 7; ++kp) {
        // ---------- row A = 2*kp: init raccs (mul for P=0, fma for P=1..6)
        {
            const unsigned* rowp = xld + (py + 2 * kp) * 33 + g * 4;
            unsigned e0 = rowp[0], e1 = rowp[1], e2 = rowp[2], e3 = rowp[3];
            unsigned e4 = rowp[4], e5 = rowp[5], e6 = rowp[6], e7 = rowp[7];
            unsigned e8 = rowp[8], e9 = rowp[9], e10 = rowp[10];
            unsigned o0 = (e0 >> 16) | (e1 << 16);
            unsigned o1 = (e1 >> 16) | (e2 << 16);
            unsigned o2 = (e2 >> 16) | (e3 << 16);
            unsigned o3 = (e3 >> 16) | (e4 << 16);
            unsigned o4 = (e4 >> 16) | (e5 << 16);
            unsigned o5 = (e5 >> 16) | (e6 << 16);
            unsigned o6 = (e6 >> 16) | (e7 << 16);
            unsigned o7 = (e7 >> 16) | (e8 << 16);
            unsigned o8 = (e8 >> 16) | (e9 << 16);
            unsigned o9 = (e9 >> 16) | (e10 << 16);
            const unsigned* kr1 = kg1 + (2 * kp) * 7;
            const unsigned* kr2 = kg2 + (2 * kp) * 7;
            unsigned ka0 = kr1[0], ka1 = kr1[1], ka2 = kr1[2], ka3 = kr1[3];
            unsigned ka4 = kr1[4], ka5 = kr1[5], ka6 = kr1[6];
            unsigned kb0 = kr2[0], kb1 = kr2[1], kb2 = kr2[2], kb3 = kr2[3];
            unsigned kb4 = kr2[4], kb5 = kr2[5], kb6 = kr2[6];
#define MQ0(RA, RB, X0, X1, X2, X3, X4, X5, X6) do { \
            RA = __hmul2(H2(X0), H2(ka0));           RB = __hmul2(H2(X0), H2(kb0)); \
            RA = __hfma2(H2(X1), H2(ka1), RA);       RB = __hfma2(H2(X1), H2(kb1), RB); \
            RA = __hfma2(H2(X2), H2(ka2), RA);       RB = __hfma2(H2(X2), H2(kb2), RB); \
            RA = __hfma2(H2(X3), H2(ka3), RA);       RB = __hfma2(H2(X3), H2(kb3), RB); \
            RA = __hfma2(H2(X4), H2(ka4), RA);       RB = __hfma2(H2(X4), H2(kb4), RB); \
            RA = __hfma2(H2(X5), H2(ka5), RA);       RB = __hfma2(H2(X5), H2(kb5), RB); \
            RA = __hfma2(H2(X6), H2(ka6), RA);       RB = __hfma2(H2(X6), H2(kb6), RB); \
            } while (0)
            MQ0(r10, r20, e0, e1, e2, e3, e4, e5, e6);
            MQ0(r11, r21, o0, o1, o2, o3, o4, o5, o6);
            MQ0(r12, r22, e1, e2, e3, e4, e5, e6, e7);
            MQ0(r13, r23, o1, o2, o3, o4, o5, o6, o7);
            MQ0(r14, r24, e2, e3, e4, e5, e6, e7, e8);
            MQ0(r15, r25, o2, o3, o4, o5, o6, o7, o8);
            MQ0(r16, r26, e3, e4, e5, e6, e7, e8, e9);
            MQ0(r17, r27, o3, o4, o5, o6, o7, o8, o9);
#undef MQ0
        }
        // ---------- row B = 2*kp+1: accumulate into raccs
        {
            const unsigned* rowp = xld + (py + 2 * kp + 1) * 33 + g * 4;
            unsigned e0 = rowp[0], e1 = rowp[1], e2 = rowp[2], e3 = rowp[3];
            unsigned e4 = rowp[4], e5 = rowp[5], e6 = rowp[6], e7 = rowp[7];
            unsigned e8 = rowp[8], e9 = rowp[9], e10 = rowp[10];
            unsigned o0 = (e0 >> 16) | (e1 << 16);
            unsigned o1 = (e1 >> 16) | (e2 << 16);
            unsigned o2 = (e2 >> 16) | (e3 << 16);
            unsigned o3 = (e3 >> 16) | (e4 << 16);
            unsigned o4 = (e4 >> 16) | (e5 << 16);
            unsigned o5 = (e5 >> 16) | (e6 << 16);
            unsigned o6 = (e6 >> 16) | (e7 << 16);
            unsigned o7 = (e7 >> 16) | (e8 << 16);
            unsigned o8 = (e8 >> 16) | (e9 << 16);
            unsigned o9 = (e9 >> 16) | (e10 << 16);
            const unsigned* kr1 = kg1 + (2 * kp + 1) * 7;
            const unsigned* kr2 = kg2 + (2 * kp + 1) * 7;
            unsigned ka0 = kr1[0], ka1 = kr1[1], ka2 = kr1[2], ka3 = kr1[3];
            unsigned ka4 = kr1[4], ka5 = kr1[5], ka6 = kr1[6];
            unsigned kb0 = kr2[0], kb1 = kr2[1], kb2 = kr2[2], kb3 = kr2[3];
            unsigned kb4 = kr2[4], kb5 = kr2[5], kb6 = kr2[6];
#define MQ(RA, RB, X0, X1, X2, X3, X4, X5, X6) do { \
            RA = __hfma2(H2(X0), H2(ka0), RA);       RB = __hfma2(H2(X0), H2(kb0), RB); \
            RA = __hfma2(H2(X1), H2(ka1), RA);       RB = __hfma2(H2(X1), H2(kb1), RB); \
            RA = __hfma2(H2(X2), H2(ka2), RA);       RB = __hfma2(H2(X2), H2(kb2), RB); \
            RA = __hfma2(H2(X3), H2(ka3), RA);       RB = __hfma2(H2(X3), H2(kb3), RB); \
            RA = __hfma2(H2(X4), H2(ka4), RA);       RB = __hfma2(H2(X4), H2(kb4), RB); \
            RA = __hfma2(H2(X5), H2(ka5), RA);       RB = __hfma2(H2(X5), H2(kb5), RB); \
            RA = __hfma2(H2(X6), H2(ka6), RA);       RB = __hfma2(H2(X6), H2(kb6), RB); \
            } while (0)
            MQ(r10, r20, e0, e1, e2, e3, e4, e5, e6);
            MQ(r11, r21, o0, o1, o2, o3, o4, o5, o6);
            MQ(r12, r22, e1, e2, e3, e4, e5, e6, e7);
            MQ(r13, r23, o1, o2, o3, o4, o5, o6, o7);
            MQ(r14, r24, e2, e3, e4, e5, e6, e7, e8);
            MQ(r15, r25, o2, o3, o4, o5, o6, o7, o8);
            MQ(r16, r26, e3, e4, e5, e6, e7, e8, e9);
            MQ(r17, r27, o3, o4, o5, o6, o7, o8, o9);
#undef MQ
        }
        // ---------- fold row-pair f16 sums into f32 accumulators (exact)
        const unsigned one2 = 0x3C003C00u;   // (1.0h, 1.0h)
        f10 = dot2f16(U2(r10), one2, f10);  f20 = dot2f16(U2(r20), one2, f20);
        f11 = dot2f16(U2(r11), one2, f11);  f21 = dot2f16(U2(r21), one2, f21);
        f12 = dot2f16(U2(r12), one2, f12);  f22 = dot2f16(U2(r22), one2, f22);
        f13 = dot2f16(U2(r13), one2, f13);  f23 = dot2f16(U2(r23), one2, f23);
        f14 = dot2f16(U2(r14), one2, f14);  f24 = dot2f16(U2(r24), one2, f24);
        f15 = dot2f16(U2(r15), one2, f15);  f25 = dot2f16(U2(r25), one2, f25);
        f16_ = dot2f16(U2(r16), one2, f16_); f26 = dot2f16(U2(r26), one2, f26);
        f17 = dot2f16(U2(r17), one2, f17);  f27 = dot2f16(U2(r27), one2, f27);
    }
#undef H2
#undef U2

    size_t ob = (size_t)bc * 2401 + (size_t)py * 49 + px0;
    out1[ob] = f10; out2[ob] = f20;
    if (px0 < 48) {
        out1[ob + 1] = f11; out1[ob + 2] = f12; out1[ob + 3] = f13;
        out1[ob + 4] = f14; out1[ob + 5] = f15; out1[ob + 6] = f16_; out1[ob + 7] = f17;
        out2[ob + 1] = f21; out2[ob + 2] = f22; out2[ob + 3] = f23;
        out2[ob + 4] = f24; out2[ob + 5] = f25; out2[ob + 6] = f26; out2[ob + 7] = f27;
    }
}

extern "C" void kernel_launch(void* const* d_in, const int* in_sizes, int n_in,
                              void* d_out, int out_size, void* d_ws, size_t ws_size,
                              hipStream_t stream) {
    const float* img = (const float*)d_in[0];
    const float* t1  = (const float*)d_in[1];
    const float* t2  = (const float*)d_in[2];
    const float* w1  = (const float*)d_in[3];
    const float* b1  = (const float*)d_in[4];
    const float* w2  = (const float*)d_in[5];
    const float* b2  = (const float*)d_in[6];
    float* out = (float*)d_out;

    char* ws = (char*)d_ws;
    __hip_bfloat16* bufA = (__hip_bfloat16*)ws;                 // 66,064,384 B
    __hip_bfloat16* w1t  = (__hip_bfloat16*)(ws + 66064384);    // 4,096 B
    __hip_bfloat16* w2h  = (__hip_bfloat16*)(ws + 66068480);    // 147,456 B
    __half* xf = (__half*)(ws + 66215936);                      // 31,490,048
    __half* k1 = (__half*)(ws + 97705984);                      // 1,605,632
    __half* k2 = (__half*)(ws + 99311616);                      // end 100,917,248

    wt_xform_all<<<296, 256, 0, stream>>>(w1, w2, w1t, w2h);

    conv1_mfma<<<dim3(256, 1, 32), 256, 0, stream>>>(img, w1t, b1, bufA,
                                                     256, 256, 127, 127, 16);
    conv2_mfma<<<dim3(128, 1, 32), 256, 0, stream>>>(bufA, w2h, b2, xf,
                                                     127, 127, 62, 62, 16);

    conv1_mfma<<<dim3(16, 1, 32), 256, 0, stream>>>(t1, w1t, b1, bufA,
                                                    64, 64, 31, 31, 4);
    conv2_mfma<<<dim3(8, 1, 32), 256, 0, stream>>>(bufA, w2h, b2, k1,
                                                   31, 31, 14, 14, 4);
    conv1_mfma<<<dim3(16, 1, 32), 256, 0, stream>>>(t2, w1t, b1, bufA,
                                                    64, 64, 31, 31, 4);
    conv2_mfma<<<dim3(8, 1, 32), 256, 0, stream>>>(bufA, w2h, b2, k2,
                                                   31, 31, 14, 14, 4);

    xcorr_dual<<<4096, 384, 0, stream>>>(xf, k1, k2, out, out + (size_t)9834496);
}

// Round 14
// 242.411 us; speedup vs baseline: 1.2392x; 1.1777x over previous
//
#include <hip/hip_runtime.h>
#include <hip/hip_bf16.h>
#include <hip/hip_fp16.h>

typedef __attribute__((ext_vector_type(8))) short bf16x8;
typedef __attribute__((ext_vector_type(8))) _Float16 f16x8;
typedef __attribute__((ext_vector_type(4))) float f32x4;

// ---------------- weight transforms -------------------------------------------
// w1 [64][3][3][3] f32 -> w1t [64][32] bf16 (k = ic*9+ky*3+kx, pad 27..31 = 0)
// w2 [128][64][3][3] f32 -> w2h [9][2][4][128][8] bf16 panels
__global__ void wt_xform_all(const float* __restrict__ w1, const float* __restrict__ w2,
                             __hip_bfloat16* __restrict__ w1t, __hip_bfloat16* __restrict__ w2h) {
    int i = blockIdx.x * 256 + threadIdx.x;
    if (i < 2048) {
        int oc = i >> 5, k = i & 31;
        w1t[i] = (k < 27) ? __float2bfloat16(w1[oc * 27 + k]) : __float2bfloat16(0.f);
        return;
    }
    int j = i - 2048;
    if (j < 9 * 2 * 4 * 128 * 8) {
        int e  = j & 7;
        int oc = (j >> 3) & 127;
        int c  = (j >> 10) & 3;
        int h  = (j >> 12) & 1;
        int kk = j >> 13;
        int ic = h * 32 + c * 8 + e;
        int ky = kk / 3, kx = kk - ky * 3;
        w2h[j] = __float2bfloat16(w2[(((size_t)oc * 64 + ic) * 3 + ky) * 3 + kx]);
    }
}

// ---------------- conv1 implicit-GEMM on MFMA + fused bias/relu/maxpool ---------
__global__ void __launch_bounds__(256, 2)
conv1_mfma(const float* __restrict__ in,
           const __hip_bfloat16* __restrict__ w1t,
           const float* __restrict__ bias,
           __hip_bfloat16* __restrict__ out,
           int Hin, int Win, int PH, int PW, int tilesX) {
    __shared__ unsigned short xs[3 * 324];   // [ic][18 rows][18 cols] bf16 bits
    int t = threadIdx.x;
    int tile = blockIdx.x;
    int tileY = tile / tilesX, tileX = tile - tileY * tilesX;
    int b = blockIdx.z;
    int y0 = tileY * 16, x0 = tileX * 16;

    const float* inb = in + (size_t)b * 3 * Hin * Win;
    for (int i = t; i < 972; i += 256) {
        int ic = i / 324, rem = i - ic * 324;
        int r = rem / 18, c = rem - r * 18;
        int gy = y0 + r, gx = x0 + c;
        float v = 0.f;
        if (gy < Hin && gx < Win) v = inb[((size_t)ic * Hin + gy) * Win + gx];
        __hip_bfloat16 hv = __float2bfloat16(v);
        xs[i] = *(unsigned short*)&hv;
    }
    __syncthreads();

    int lane = t & 63, wv = t >> 6;
    int l15 = lane & 15, l4 = lane >> 4;

    bf16x8 af[4];
#pragma unroll
    for (int m = 0; m < 4; ++m)
        af[m] = *(const bf16x8*)&w1t[((size_t)(m * 16 + l15)) * 32 + l4 * 8];

    int off0, off1, off2, off3, off4, off5, off6, off7;
    int ok0, ok1, ok2, ok3, ok4, ok5, ok6, ok7;
#define MKOFF(J) { int kk = l4 * 8 + J; int ic = kk / 9; int r9 = kk - ic * 9; \
                   int ky = r9 / 3; int kx = r9 - ky * 3; \
                   ok##J = (kk < 27); off##J = ok##J ? (ic * 324 + ky * 18 + kx) : 0; }
    MKOFF(0) MKOFF(1) MKOFF(2) MKOFF(3) MKOFF(4) MKOFF(5) MKOFF(6) MKOFF(7)
#undef MKOFF

    f32x4 acc[4][4];
#pragma unroll
    for (int m = 0; m < 4; ++m)
#pragma unroll
        for (int n = 0; n < 4; ++n) acc[m][n] = (f32x4)(0.f);

#pragma unroll
    for (int n = 0; n < 4; ++n) {
        int y = wv * 4 + n;
        int base = y * 18 + l15;
        bf16x8 bfr;
        bfr[0] = ok0 ? (short)xs[base + off0] : (short)0;
        bfr[1] = ok1 ? (short)xs[base + off1] : (short)0;
        bfr[2] = ok2 ? (short)xs[base + off2] : (short)0;
        bfr[3] = ok3 ? (short)xs[base + off3] : (short)0;
        bfr[4] = ok4 ? (short)xs[base + off4] : (short)0;
        bfr[5] = ok5 ? (short)xs[base + off5] : (short)0;
        bfr[6] = ok6 ? (short)xs[base + off6] : (short)0;
        bfr[7] = ok7 ? (short)xs[base + off7] : (short)0;
#pragma unroll
        for (int m = 0; m < 4; ++m)
            acc[m][n] = __builtin_amdgcn_mfma_f32_16x16x32_bf16(af[m], bfr, acc[m][n], 0, 0, 0);
    }

    int qx = tileX * 8 + (l15 >> 1);
    bool xok = ((lane & 1) == 0) && (qx < PW);
#pragma unroll
    for (int m = 0; m < 4; ++m) {
        int ocb = m * 16 + l4 * 4;
#pragma unroll
        for (int np = 0; np < 2; ++np) {
            int qy = tileY * 8 + wv * 2 + np;
            union { __hip_bfloat16 h[4]; uint2 v; } pk;
#pragma unroll
            for (int r = 0; r < 4; ++r) {
                float v = fmaxf(acc[m][2 * np][r], acc[m][2 * np + 1][r]);
                v = fmaxf(v, __shfl_xor(v, 1));
                pk.h[r] = __float2bfloat16(fmaxf(v + bias[ocb + r], 0.f));
            }
            if (xok && qy < PH)
                *(uint2*)&out[(((size_t)b * PH + qy) * PW + qx) * 64 + ocb] = pk.v;
        }
    }
}

// ---------------- conv2 implicit-GEMM: 18-phase ic-half A-dbuf, 4 blocks/CU ------
__global__ void __launch_bounds__(256, 4)
conv2_mfma(const __hip_bfloat16* __restrict__ xin,
           const __hip_bfloat16* __restrict__ w2h,
           const float* __restrict__ bias, __half* __restrict__ out,
           int H1, int W1, int PH, int PW, int tilesY) {
    __shared__ uint4 xl4[10 * 18 * 8];   // 23040 B input tile; reused as store buffer
    __shared__ uint4 aw[2][512];         // 2 x 8 KB weight half-panels

    int t = threadIdx.x;
    int tile = blockIdx.x;
    int tileY = tile % tilesY, tileX = tile / tilesY;
    int b = blockIdx.z;
    int y0 = tileY * 8, x0 = tileX * 16;

    const __hip_bfloat16* xb = xin + (size_t)b * H1 * W1 * 64;
    for (int s = t; s < 1440; s += 256) {
        int pixel = s >> 3, si = s & 7;
        int row = pixel / 18, col = pixel - row * 18;
        int gy = y0 + row, gx = x0 + col;
        uint4 v = make_uint4(0, 0, 0, 0);
        if (gy < H1 && gx < W1)
            v = *(const uint4*)&xb[((size_t)gy * W1 + gx) * 64 + si * 8];
        xl4[(pixel << 3) | (si ^ (col & 7))] = v;
    }
    {
        const uint4* src = (const uint4*)w2h;
        aw[0][t] = src[t];
        aw[0][t + 256] = src[t + 256];
    }
    __syncthreads();

    int lane = t & 63;
    int wid = t >> 6;
    int wr = wid >> 1;
    int wc = wid & 1;
    int l15 = lane & 15, l4 = lane >> 4;

    f32x4 acc[4][4];
#pragma unroll
    for (int m = 0; m < 4; ++m)
#pragma unroll
        for (int n = 0; n < 4; ++n) acc[m][n] = (f32x4)(0.f);

    for (int p = 0; p < 18; ++p) {
        const int cur = p & 1;
        const int kk = p >> 1, h = p & 1;

        uint4 pf0, pf1;
        if (p < 17) {
            const uint4* src = (const uint4*)w2h + (size_t)(p + 1) * 512;
            pf0 = src[t];
            pf1 = src[t + 256];
        }

        const int ky = kk / 3, kx = kk - ky * 3;
        const int col = l15 + kx;
        const int sidx = (h * 4 + l4) ^ (col & 7);

        bf16x8 af[4], bfv[4];
#pragma unroll
        for (int m = 0; m < 4; ++m) {
            int oc = wr * 64 + m * 16 + l15;
            af[m] = *(const bf16x8*)&aw[cur][l4 * 128 + oc];
        }
#pragma unroll
        for (int n = 0; n < 4; ++n) {
            int row = wc * 4 + n + ky;
            bfv[n] = *(const bf16x8*)&xl4[((row * 18 + col) << 3) | sidx];
        }
#pragma unroll
        for (int m = 0; m < 4; ++m)
#pragma unroll
            for (int n = 0; n < 4; ++n)
                acc[m][n] = __builtin_amdgcn_mfma_f32_16x16x32_bf16(
                    af[m], bfv[n], acc[m][n], 0, 0, 0);

        if (p < 17) {
            aw[cur ^ 1][t] = pf0;
            aw[cur ^ 1][t + 256] = pf1;
        }
        __syncthreads();
    }

    __half* plds = (__half*)xl4;
#pragma unroll
    for (int m = 0; m < 4; ++m) {
        int ocb = wr * 64 + m * 16 + l4 * 4;
#pragma unroll
        for (int np = 0; np < 2; ++np) {
            int qyl = wc * 2 + np;
#pragma unroll
            for (int r = 0; r < 4; ++r) {
                float v = fmaxf(acc[m][2 * np][r], acc[m][2 * np + 1][r]);
                v = fmaxf(v, __shfl_xor(v, 1));
                if ((lane & 1) == 0) {
                    float u = fmaxf(v + bias[ocb + r], 0.f);
                    plds[((ocb + r) * 4 + qyl) * 8 + (l15 >> 1)] = __float2half(u);
                }
            }
        }
    }
    __syncthreads();

    int qx0 = tileX * 8, qy0 = tileY * 4;
    for (int i = t; i < 512; i += 256) {
        int oc = i >> 2, qy = i & 3;
        int gqy = qy0 + qy;
        if (gqy < PH) {
            __half* dst = out + (((size_t)b * 128 + oc) * PH + gqy) * PW + qx0;
            const __half* src = &plds[i * 8];
            if (qx0 + 8 <= PW) {
                *(uint4*)dst = *(const uint4*)src;
            } else {
                for (int q = 0; q < 8 && qx0 + q < PW; ++q) dst[q] = src[q];
            }
        }
    }
}

// ---------------- dual depthwise xcorr on MFMA (shift-in-M formulation) ----------
// R13 lesson: the k-staging loop assumed 392 threads but blockDim=256 -> k2 rows
// 4..13 stayed zero (out1 passed, out2 absmax 642). Now a strided loop.
// Layout (validated by out1 passing in R13): A[m=(j,s)][k=(ky,kx)] =
// kern_j[ky-s][kx], B[k][n] = x[py0+ky][px0+n+kx], C[(j,s)][n] =
// out_j[py0+s][px0+n]. 4 parity-shifted LDS copies -> aligned 8B reads at
// 2-byte column granularity. Overlap tiles -> bounds-free stores.
__global__ void __launch_bounds__(256, 4)
xcorr_mfma(const __half* __restrict__ x, const __half* __restrict__ k1,
           const __half* __restrict__ k2,
           float* __restrict__ out1, float* __restrict__ out2) {
    // 4 copies x 8704 B (64 rows x 68 f16, pitch 136 B) at stride 8720 (+16 skew)
    // + klds [2][14][16] f16 (896 B) at 34880. Total 35776 B.
    __shared__ __align__(16) char smem[35776];
    int bc = blockIdx.x, t = threadIdx.x;

    unsigned* c0p = (unsigned*)smem;   // copy0, dword view, row pitch 34 dwords
    const unsigned* xp = (const unsigned*)(x + (size_t)bc * 3844);   // 62x31 dwords
    for (int idx = t; idx < 64 * 34; idx += 256) {
        int r = idx / 34, i = idx - r * 34;
        unsigned v = 0;
        if (r < 62 && i < 31) v = xp[r * 31 + i];
        c0p[r * 34 + i] = v;
    }
    __half* kl = (__half*)(smem + 34880);
    if (t < 224) ((unsigned*)kl)[t] = 0;       // zero incl. kx=14,15 pad
    __syncthreads();

    // kernels -> klds [j][row][16]  (392 items, 256 threads -> strided loop!)
    for (int idx = t; idx < 392; idx += 256) {
        int j = idx / 196, r196 = idx - j * 196;
        int kr = r196 / 14, kc = r196 - kr * 14;
        const __half* kg = (j == 0 ? k1 : k2) + (size_t)bc * 196;
        kl[(j * 14 + kr) * 16 + kc] = kg[r196];
    }
    // derive parity copies 1..3 from copy0
    for (int idx = t; idx < 64 * 34; idx += 256) {
        int r = idx / 34, i = idx - r * 34;
        unsigned d0 = c0p[r * 34 + i];
        unsigned d1 = (i < 33) ? c0p[r * 34 + i + 1] : 0u;
        unsigned d2 = (i < 32) ? c0p[r * 34 + i + 2] : 0u;
        int ro = r * 136 + i * 4;
        *(unsigned*)(smem +  8720 + ro) = (d0 >> 16) | (d1 << 16);
        *(unsigned*)(smem + 17440 + ro) = d1;
        *(unsigned*)(smem + 26160 + ro) = (d1 >> 16) | (d2 << 16);
    }
    __syncthreads();

    int lane = t & 63, wid = t >> 6;
    int l15 = lane & 15, l4 = lane >> 4;

    // A fragments: lane's A-row m = l15 -> (j = m>>3, s = m&7); k-slice l4*8+j'
    // -> ky = 2kp + (l4>>1), kx = (l4&1)*8 + j'
    int jm = l15 >> 3, sm = l15 & 7;
    f16x8 zf = (f16x8)(_Float16)0;
    f16x8 af[11];
#pragma unroll
    for (int kp = 0; kp < 11; ++kp) {
        int ky = 2 * kp + (l4 >> 1);
        int rr = ky - sm;
        int rc = min(max(rr, 0), 13);
        f16x8 v = *(const f16x8*)&kl[(jm * 14 + rc) * 16 + (l4 & 1) * 8];
        af[kp] = (rr >= 0 && rr < 14) ? v : zf;
    }

    int cbase = (l4 & 1) * 8 + l15;   // column offset from px0
    int rhalf = l4 >> 1;

    for (int tt = wid; tt < 28; tt += 4) {
        int u = tt % 7, q = tt / 7;
        int py0 = (u < 6) ? u * 8 : 41;
        int px0 = (q < 2) ? q * 16 : (q == 2 ? 32 : 33);

        int c0 = px0 + cbase;
        int p = c0 & 3;
        const char* baddr = smem + p * 8720 + (py0 + rhalf) * 136 + ((c0 - p) >> 2) * 8;

        f32x4 acc = (f32x4)(0.f);
#pragma unroll
        for (int kp = 0; kp < 11; ++kp) {
            union { uint2 u2[2]; f16x8 v; } bu;
            bu.u2[0] = *(const uint2*)(baddr + kp * 272);
            bu.u2[1] = *(const uint2*)(baddr + kp * 272 + 8);
            acc = __builtin_amdgcn_mfma_f32_16x16x32_f16(af[kp], bu.v, acc, 0, 0, 0);
        }

        // C: col = l15 (px), row = l4*4 + r -> (j = row>>3, s = row&7)
        int px = px0 + l15;
#pragma unroll
        for (int r = 0; r < 4; ++r) {
            int m = l4 * 4 + r;
            float* ob = (m >> 3) ? out2 : out1;
            ob[(size_t)bc * 2401 + (size_t)(py0 + (m & 7)) * 49 + px] = acc[r];
        }
    }
}

extern "C" void kernel_launch(void* const* d_in, const int* in_sizes, int n_in,
                              void* d_out, int out_size, void* d_ws, size_t ws_size,
                              hipStream_t stream) {
    const float* img = (const float*)d_in[0];
    const float* t1  = (const float*)d_in[1];
    const float* t2  = (const float*)d_in[2];
    const float* w1  = (const float*)d_in[3];
    const float* b1  = (const float*)d_in[4];
    const float* w2  = (const float*)d_in[5];
    const float* b2  = (const float*)d_in[6];
    float* out = (float*)d_out;

    char* ws = (char*)d_ws;
    __hip_bfloat16* bufA = (__hip_bfloat16*)ws;                 // 66,064,384 B
    __hip_bfloat16* w1t  = (__hip_bfloat16*)(ws + 66064384);    // 4,096 B
    __hip_bfloat16* w2h  = (__hip_bfloat16*)(ws + 66068480);    // 147,456 B
    __half* xf = (__half*)(ws + 66215936);                      // 31,490,048
    __half* k1 = (__half*)(ws + 97705984);                      // 1,605,632
    __half* k2 = (__half*)(ws + 99311616);                      // end 100,917,248

    wt_xform_all<<<296, 256, 0, stream>>>(w1, w2, w1t, w2h);

    conv1_mfma<<<dim3(256, 1, 32), 256, 0, stream>>>(img, w1t, b1, bufA,
                                                     256, 256, 127, 127, 16);
    conv2_mfma<<<dim3(128, 1, 32), 256, 0, stream>>>(bufA, w2h, b2, xf,
                                                     127, 127, 62, 62, 16);

    conv1_mfma<<<dim3(16, 1, 32), 256, 0, stream>>>(t1, w1t, b1, bufA,
                                                    64, 64, 31, 31, 4);
    conv2_mfma<<<dim3(8, 1, 32), 256, 0, stream>>>(bufA, w2h, b2, k1,
                                                   31, 31, 14, 14, 4);
    conv1_mfma<<<dim3(16, 1, 32), 256, 0, stream>>>(t2, w1t, b1, bufA,
                                                    64, 64, 31, 31, 4);
    conv2_mfma<<<dim3(8, 1, 32), 256, 0, stream>>>(bufA, w2h, b2, k2,
                                                   31, 31, 14, 14, 4);

    xcorr_mfma<<<4096, 256, 0, stream>>>(xf, k1, k2, out, out + (size_t)9834496);
}